// Round 10
// baseline (224.226 us; speedup 1.0000x reference)
//
#include <hip/hip_runtime.h>
#include <math.h>

// ---------------- small utils ----------------
__global__ void zero32(int* __restrict__ p, int n) {
    int i = blockIdx.x * blockDim.x + threadIdx.x;
    if (i < n) p[i] = 0;
}

// ---------------- degree / dinv ----------------
__global__ void hist_dst(const int* __restrict__ dst, int* __restrict__ cnt, int E) {
    int e = blockIdx.x * blockDim.x + threadIdx.x;
    if (e < E) atomicAdd(&cnt[dst[e]], 1);
}

__global__ void dinv_from_cnt(const int* __restrict__ cnt, float* __restrict__ dinv, int n) {
    int v = blockIdx.x * blockDim.x + threadIdx.x;
    if (v < n) dinv[v] = rsqrtf((float)(cnt[v] + 1));  // +1 self-loop
}

// ---- hierarchical scan: 256-elem chunks ----
__global__ __launch_bounds__(256) void scan1(const int* __restrict__ cnt,
                                             int* __restrict__ excl,
                                             int* __restrict__ sums, int n) {
    int i = blockIdx.x * 256 + threadIdx.x;
    int v = (i < n) ? cnt[i] : 0;
    int lane = threadIdx.x & 63;
    int w = threadIdx.x >> 6;
    int s = v;
#pragma unroll
    for (int off = 1; off < 64; off <<= 1) {
        int t = __shfl_up(s, off, 64);
        if (lane >= off) s += t;
    }
    __shared__ int wsum[4];
    if (lane == 63) wsum[w] = s;
    __syncthreads();
    int woff = 0;
#pragma unroll
    for (int k = 0; k < 3; ++k) if (k < w) woff += wsum[k];
    int incl = s + woff;
    if (i < n) excl[i] = incl - v;
    if (threadIdx.x == 255) sums[blockIdx.x] = incl;
}

__global__ __launch_bounds__(256) void scan2(int* __restrict__ sums, int nb) {
    int t = threadIdx.x;
    int v = (t < nb) ? sums[t] : 0;
    int lane = t & 63;
    int w = t >> 6;
    int s = v;
#pragma unroll
    for (int off = 1; off < 64; off <<= 1) {
        int u = __shfl_up(s, off, 64);
        if (lane >= off) s += u;
    }
    __shared__ int wsum[4];
    if (lane == 63) wsum[w] = s;
    __syncthreads();
    int woff = 0;
#pragma unroll
    for (int k = 0; k < 3; ++k) if (k < w) woff += wsum[k];
    int incl = s + woff;
    if (t < nb) sums[t] = incl - v;  // exclusive
}

__global__ __launch_bounds__(256) void scan3(const int* __restrict__ excl,
                                             const int* __restrict__ sums,
                                             int* __restrict__ rowptr,
                                             int* __restrict__ cursor, int n, int E) {
    int i = blockIdx.x * 256 + threadIdx.x;
    if (i < n) {
        int r = excl[i] + sums[i >> 8];
        rowptr[i] = r;
        cursor[i] = r;
    }
    if (i == n) rowptr[n] = E;
}

// XCD-partitioned fill. Payload is just src as ushort (needs n < 65536):
// edge weight dinv[s]*dinv[d] is factored into pre-scaled features instead.
// Each XCD slice writes a ~200KB L2-resident region -> no write amplification.
__global__ void fill_col16(const int* __restrict__ src, const int* __restrict__ dst,
                           int* __restrict__ cursor, unsigned short* __restrict__ col,
                           int E, int n) {
    const int g    = blockIdx.x & 7;
    const int nblk = gridDim.x >> 3;
    const int bid  = blockIdx.x >> 3;
    const int lo = (int)(((long)g * n) >> 3);
    const int hi = (int)(((long)(g + 1) * n) >> 3);
    for (long e = (long)bid * blockDim.x + threadIdx.x; e < E;
         e += (long)nblk * blockDim.x) {
        int d = dst[e];
        if (d < lo || d >= hi) continue;
        int p = atomicAdd(&cursor[d], 1);
        col[p] = (unsigned short)src[e];
    }
}

// ---------------- GEMM1: Y[n,64] = dinv[r] * (X[n,128] @ W[128,64]) ----------------
// Wave owns a row; lane owns output column; W column in VGPRs; X row broadcast
// via v_readlane (SALU, co-issues with VALU). Writes dinv-scaled features.
template <int K>
__global__ __launch_bounds__(256) void gemm_bcast_scaled(const float* __restrict__ X,
                                                         const float* __restrict__ W,
                                                         const float* __restrict__ dinv,
                                                         float* __restrict__ Y, int n) {
    const int lane = threadIdx.x & 63;
    const long wid = (((long)blockIdx.x * blockDim.x) + threadIdx.x) >> 6;
    const long nw  = ((long)gridDim.x * blockDim.x) >> 6;

    float wr[K];
#pragma unroll
    for (int k = 0; k < K; ++k) wr[k] = W[k * 64 + lane];

    long r = wid;
    if (r >= n) return;
    float xa = X[r * K + lane];
    float xb = 0.f;
    if constexpr (K > 64) xb = X[r * K + 64 + lane];
    float dv = dinv[r];

    while (true) {
        long rn = r + nw;
        bool more = rn < n;
        long rc = more ? rn : r;
        float xan = X[rc * K + lane];
        float xbn = 0.f;
        if constexpr (K > 64) xbn = X[rc * K + 64 + lane];
        float dvn = dinv[rc];

        float a0 = 0.f, a1 = 0.f, a2 = 0.f, a3 = 0.f;
#pragma unroll
        for (int k = 0; k < 64; k += 4) {
            a0 = fmaf(__int_as_float(__builtin_amdgcn_readlane(__float_as_int(xa), k + 0)), wr[k + 0], a0);
            a1 = fmaf(__int_as_float(__builtin_amdgcn_readlane(__float_as_int(xa), k + 1)), wr[k + 1], a1);
            a2 = fmaf(__int_as_float(__builtin_amdgcn_readlane(__float_as_int(xa), k + 2)), wr[k + 2], a2);
            a3 = fmaf(__int_as_float(__builtin_amdgcn_readlane(__float_as_int(xa), k + 3)), wr[k + 3], a3);
        }
        if constexpr (K > 64) {
#pragma unroll
            for (int k = 0; k < 64; k += 4) {
                a0 = fmaf(__int_as_float(__builtin_amdgcn_readlane(__float_as_int(xb), k + 0)), wr[64 + k + 0], a0);
                a1 = fmaf(__int_as_float(__builtin_amdgcn_readlane(__float_as_int(xb), k + 1)), wr[64 + k + 1], a1);
                a2 = fmaf(__int_as_float(__builtin_amdgcn_readlane(__float_as_int(xb), k + 2)), wr[64 + k + 2], a2);
                a3 = fmaf(__int_as_float(__builtin_amdgcn_readlane(__float_as_int(xb), k + 3)), wr[64 + k + 3], a3);
            }
        }
        Y[r * 64 + lane] = dv * ((a0 + a1) + (a2 + a3));
        if (!more) break;
        r = rn;
        xa = xan;
        xb = xbn;
        dv = dvn;
    }
}

// unweighted gather-sum over the node's edge list (unroll 8, packed ushort cols)
#define AGG_SUM_BODY(HP)                                                     \
    float acc0 = HP[v * 64 + j];  /* self-loop: h'[v] */                     \
    float acc1 = 0.f, acc2 = 0.f, acc3 = 0.f;                                \
    int p = rowptr[v], p1 = rowptr[v + 1];                                   \
    if ((p & 1) && p < p1) { acc1 += HP[(long)col[p] * 64 + j]; ++p; }       \
    for (; p + 8 <= p1; p += 8) {                                            \
        unsigned int c01 = *(const unsigned int*)(col + p);                  \
        unsigned int c23 = *(const unsigned int*)(col + p + 2);              \
        unsigned int c45 = *(const unsigned int*)(col + p + 4);              \
        unsigned int c67 = *(const unsigned int*)(col + p + 6);              \
        float h0 = HP[(long)(c01 & 0xFFFFu) * 64 + j];                       \
        float h1 = HP[(long)(c01 >> 16) * 64 + j];                           \
        float h2 = HP[(long)(c23 & 0xFFFFu) * 64 + j];                       \
        float h3 = HP[(long)(c23 >> 16) * 64 + j];                           \
        float h4 = HP[(long)(c45 & 0xFFFFu) * 64 + j];                       \
        float h5 = HP[(long)(c45 >> 16) * 64 + j];                           \
        float h6 = HP[(long)(c67 & 0xFFFFu) * 64 + j];                       \
        float h7 = HP[(long)(c67 >> 16) * 64 + j];                           \
        acc0 += h0; acc1 += h1; acc2 += h2; acc3 += h3;                      \
        acc0 += h4; acc1 += h5; acc2 += h6; acc3 += h7;                      \
    }                                                                        \
    for (; p < p1; ++p) acc1 += HP[(long)col[p] * 64 + j];

// ---------------- layer1-agg + layer2-GEMM fused ----------------
// g1 = relu(dinv[v]*(sum + self) + b1);  out = dinv[v]*(g1 @ W2)  (pre-scaled h2')
__global__ __launch_bounds__(256) void agg_gemm64(const float* __restrict__ Hp,
                                                  const int* __restrict__ rowptr,
                                                  const unsigned short* __restrict__ col,
                                                  const float* __restrict__ dinv,
                                                  const float* __restrict__ bias,
                                                  const float* __restrict__ W2,
                                                  float* __restrict__ out, int n) {
    const int j = threadIdx.x & 63;
    const long wid = (((long)blockIdx.x * blockDim.x) + threadIdx.x) >> 6;
    const long nw  = ((long)gridDim.x * blockDim.x) >> 6;
    float wr[64];
#pragma unroll
    for (int k = 0; k < 64; ++k) wr[k] = W2[k * 64 + j];
    const float bj = bias[j];
    for (long v = wid; v < n; v += nw) {
        float di = dinv[v];
        AGG_SUM_BODY(Hp)
        float g = fmaxf(di * ((acc0 + acc1) + (acc2 + acc3)) + bj, 0.f);
        float a0 = 0.f, a1 = 0.f, a2 = 0.f, a3 = 0.f;
#pragma unroll
        for (int k = 0; k < 64; k += 4) {
            a0 = fmaf(__int_as_float(__builtin_amdgcn_readlane(__float_as_int(g), k + 0)), wr[k + 0], a0);
            a1 = fmaf(__int_as_float(__builtin_amdgcn_readlane(__float_as_int(g), k + 1)), wr[k + 1], a1);
            a2 = fmaf(__int_as_float(__builtin_amdgcn_readlane(__float_as_int(g), k + 2)), wr[k + 2], a2);
            a3 = fmaf(__int_as_float(__builtin_amdgcn_readlane(__float_as_int(g), k + 3)), wr[k + 3], a3);
        }
        out[v * 64 + j] = di * ((a0 + a1) + (a2 + a3));
    }
}

// ---------------- layer2-agg + head-dot + pool fused ----------------
// z = relu(dinv[v]*(sum+self)+b2) . Wl ; accumulate into per-block LDS bins,
// write per-block partials (no global atomics).
__global__ __launch_bounds__(256) void agg_pool(const float* __restrict__ Hp,
                                                const int* __restrict__ rowptr,
                                                const unsigned short* __restrict__ col,
                                                const float* __restrict__ dinv,
                                                const float* __restrict__ bias,
                                                const float* __restrict__ Wl,
                                                const int* __restrict__ batch,
                                                float* __restrict__ part,
                                                float* __restrict__ partc, int n) {
    __shared__ float lp[256];
    __shared__ float lc[256];
    lp[threadIdx.x] = 0.f;
    lc[threadIdx.x] = 0.f;
    __syncthreads();
    const int j  = threadIdx.x & 63;
    const int wv = threadIdx.x >> 6;
    const float bj  = bias[j];
    const float wlj = Wl[j];
    for (long v = (long)blockIdx.x * 4 + wv; v < n; v += (long)gridDim.x * 4) {
        float di = dinv[v];
        AGG_SUM_BODY(Hp)
        float val = fmaxf(di * ((acc0 + acc1) + (acc2 + acc3)) + bj, 0.f) * wlj;
#pragma unroll
        for (int off = 32; off > 0; off >>= 1) val += __shfl_down(val, off, 64);
        if (j == 0) {
            int g = batch[v];
            atomicAdd(&lp[g], val);
            atomicAdd(&lc[g], 1.0f);
        }
    }
    __syncthreads();
    long o = (long)blockIdx.x * 256 + threadIdx.x;
    part[o]  = lp[threadIdx.x];
    partc[o] = lc[threadIdx.x];
}

__global__ __launch_bounds__(256) void pool_final(const float* __restrict__ part,
                                                  const float* __restrict__ partc,
                                                  const float* __restrict__ bl,
                                                  float* __restrict__ out, int nblk) {
    int g = blockIdx.x;
    int t = threadIdx.x;
    float s = 0.f, c = 0.f;
    for (int b = t; b < nblk; b += 256) {
        s += part[(long)b * 256 + g];
        c += partc[(long)b * 256 + g];
    }
    __shared__ float sp[256];
    __shared__ float sc[256];
    sp[t] = s;
    sc[t] = c;
    __syncthreads();
    for (int off = 128; off > 0; off >>= 1) {
        if (t < off) { sp[t] += sp[t + off]; sc[t] += sc[t + off]; }
        __syncthreads();
    }
    if (t == 0) out[g] = sp[0] / fmaxf(sc[0], 1.0f) + bl[0];
}

extern "C" void kernel_launch(void* const* d_in, const int* in_sizes, int n_in,
                              void* d_out, int out_size, void* d_ws, size_t ws_size,
                              hipStream_t stream) {
    const float* x  = (const float*)d_in[0];
    const float* W1 = (const float*)d_in[1];
    const float* b1 = (const float*)d_in[2];
    const float* W2 = (const float*)d_in[3];
    const float* b2 = (const float*)d_in[4];
    const float* Wl = (const float*)d_in[5];
    const float* bl = (const float*)d_in[6];
    const int* edge_index = (const int*)d_in[7];
    const int* batch      = (const int*)d_in[8];

    const int n = in_sizes[0] / 128;   // 50000  (< 65536 required for ushort cols)
    const int E = in_sizes[7] / 2;     // 800000
    const int G = out_size;            // 256
    const int* src = edge_index;
    const int* dst = edge_index + E;

    char* ws = (char*)d_ws;
    size_t off = 0;
    auto alloc = [&](size_t bytes) { void* p = ws + off; off = (off + bytes + 255) & ~(size_t)255; return p; };
    int*            cntv   = (int*)           alloc((size_t)n * 4);
    float*          dinv   = (float*)         alloc((size_t)n * 4);
    int*            rowptr = (int*)           alloc((size_t)(n + 1) * 4);
    int*            cursor = (int*)           alloc((size_t)n * 4);
    int*            excl   = (int*)           alloc((size_t)n * 4);
    int*            sums   = (int*)           alloc((size_t)256 * 4);
    unsigned short* col    = (unsigned short*)alloc((size_t)E * 2);
    float*          bufA   = (float*)         alloc((size_t)n * 64 * 4);
    float*          bufB   = (float*)         alloc((size_t)n * 64 * 4);
    const int PBLK = 2048;
    float*          part   = (float*)         alloc((size_t)PBLK * 256 * 4);
    float*          partc  = (float*)         alloc((size_t)PBLK * 256 * 4);

    const int T = 256;
    const int nchunks = (n + 255) / 256;  // 196 <= 256
    // ---- CSR build (shared by both layers) ----
    zero32<<<(n + T - 1) / T, T, 0, stream>>>(cntv, n);
    hist_dst<<<(E + T - 1) / T, T, 0, stream>>>(dst, cntv, E);
    dinv_from_cnt<<<(n + T - 1) / T, T, 0, stream>>>(cntv, dinv, n);
    scan1<<<nchunks, T, 0, stream>>>(cntv, excl, sums, n);
    scan2<<<1, T, 0, stream>>>(sums, nchunks);
    scan3<<<(n + 1 + T - 1) / T, T, 0, stream>>>(excl, sums, rowptr, cursor, n, E);
    fill_col16<<<1024, T, 0, stream>>>(src, dst, cursor, col, E, n);

    // ---- layer 1 GEMM (writes dinv-scaled h1') ----
    gemm_bcast_scaled<128><<<768, T, 0, stream>>>(x, W1, dinv, bufA, n);
    // ---- layer1-agg + layer2-GEMM fused (writes dinv-scaled h2') ----
    agg_gemm64<<<2048, T, 0, stream>>>(bufA, rowptr, col, dinv, b1, W2, bufB, n);
    // ---- layer2-agg + head + pooling partials ----
    agg_pool<<<PBLK, T, 0, stream>>>(bufB, rowptr, col, dinv, b2, Wl, batch, part, partc, n);
    pool_final<<<G, T, 0, stream>>>(part, partc, bl, (float*)d_out, PBLK);
}

// Round 11
// 211.005 us; speedup vs baseline: 1.0627x; 1.0627x over previous
//
#include <hip/hip_runtime.h>
#include <math.h>

// ---------------- small utils ----------------
__global__ void zero32(int* __restrict__ p, int n) {
    int i = blockIdx.x * blockDim.x + threadIdx.x;
    if (i < n) p[i] = 0;
}

// ---------------- degree / dinv ----------------
__global__ void hist_dst(const int* __restrict__ dst, int* __restrict__ cnt, int E) {
    int e = blockIdx.x * blockDim.x + threadIdx.x;
    if (e < E) atomicAdd(&cnt[dst[e]], 1);
}

__global__ void dinv_from_cnt(const int* __restrict__ cnt, float* __restrict__ dinv, int n) {
    int v = blockIdx.x * blockDim.x + threadIdx.x;
    if (v < n) dinv[v] = rsqrtf((float)(cnt[v] + 1));  // +1 self-loop
}

// ---- hierarchical scan: 256-elem chunks ----
__global__ __launch_bounds__(256) void scan1(const int* __restrict__ cnt,
                                             int* __restrict__ excl,
                                             int* __restrict__ sums, int n) {
    int i = blockIdx.x * 256 + threadIdx.x;
    int v = (i < n) ? cnt[i] : 0;
    int lane = threadIdx.x & 63;
    int w = threadIdx.x >> 6;
    int s = v;
#pragma unroll
    for (int off = 1; off < 64; off <<= 1) {
        int t = __shfl_up(s, off, 64);
        if (lane >= off) s += t;
    }
    __shared__ int wsum[4];
    if (lane == 63) wsum[w] = s;
    __syncthreads();
    int woff = 0;
#pragma unroll
    for (int k = 0; k < 3; ++k) if (k < w) woff += wsum[k];
    int incl = s + woff;
    if (i < n) excl[i] = incl - v;
    if (threadIdx.x == 255) sums[blockIdx.x] = incl;
}

__global__ __launch_bounds__(256) void scan2(int* __restrict__ sums, int nb) {
    int t = threadIdx.x;
    int v = (t < nb) ? sums[t] : 0;
    int lane = t & 63;
    int w = t >> 6;
    int s = v;
#pragma unroll
    for (int off = 1; off < 64; off <<= 1) {
        int u = __shfl_up(s, off, 64);
        if (lane >= off) s += u;
    }
    __shared__ int wsum[4];
    if (lane == 63) wsum[w] = s;
    __syncthreads();
    int woff = 0;
#pragma unroll
    for (int k = 0; k < 3; ++k) if (k < w) woff += wsum[k];
    int incl = s + woff;
    if (t < nb) sums[t] = incl - v;  // exclusive
}

__global__ __launch_bounds__(256) void scan3(const int* __restrict__ excl,
                                             const int* __restrict__ sums,
                                             int* __restrict__ rowptr,
                                             int* __restrict__ cursor, int n, int E) {
    int i = blockIdx.x * 256 + threadIdx.x;
    if (i < n) {
        int r = excl[i] + sums[i >> 8];
        rowptr[i] = r;
        cursor[i] = r;
    }
    if (i == n) rowptr[n] = E;
}

// XCD-partitioned fill; payload = src as ushort (n < 65536), weights factored
// into pre-scaled features.
__global__ void fill_col16(const int* __restrict__ src, const int* __restrict__ dst,
                           int* __restrict__ cursor, unsigned short* __restrict__ col,
                           int E, int n) {
    const int g    = blockIdx.x & 7;
    const int nblk = gridDim.x >> 3;
    const int bid  = blockIdx.x >> 3;
    const int lo = (int)(((long)g * n) >> 3);
    const int hi = (int)(((long)(g + 1) * n) >> 3);
    for (long e = (long)bid * blockDim.x + threadIdx.x; e < E;
         e += (long)nblk * blockDim.x) {
        int d = dst[e];
        if (d < lo || d >= hi) continue;
        int p = atomicAdd(&cursor[d], 1);
        col[p] = (unsigned short)src[e];
    }
}

#define RL(x, k) __int_as_float(__builtin_amdgcn_readlane(__float_as_int(x), (k)))

// ---------------- GEMM1: Y[n,64] = dinv[r] * (X[n,128] @ W[128,64]) ----------------
template <int K>
__global__ __launch_bounds__(256) void gemm_bcast_scaled(const float* __restrict__ X,
                                                         const float* __restrict__ W,
                                                         const float* __restrict__ dinv,
                                                         float* __restrict__ Y, int n) {
    const int lane = threadIdx.x & 63;
    const long wid = (((long)blockIdx.x * blockDim.x) + threadIdx.x) >> 6;
    const long nw  = ((long)gridDim.x * blockDim.x) >> 6;

    float wr[K];
#pragma unroll
    for (int k = 0; k < K; ++k) wr[k] = W[k * 64 + lane];
#pragma unroll
    for (int k = 0; k < K; ++k) asm volatile("" : "+v"(wr[k]));  // pin in VGPRs

    long r = wid;
    if (r >= n) return;
    float xa = X[r * K + lane];
    float xb = 0.f;
    if constexpr (K > 64) xb = X[r * K + 64 + lane];
    float dv = dinv[r];

    while (true) {
        long rn = r + nw;
        bool more = rn < n;
        long rc = more ? rn : r;
        float xan = X[rc * K + lane];
        float xbn = 0.f;
        if constexpr (K > 64) xbn = X[rc * K + 64 + lane];
        float dvn = dinv[rc];

        float a0 = 0.f, a1 = 0.f, a2 = 0.f, a3 = 0.f;
#pragma unroll
        for (int k = 0; k < 64; k += 4) {
            a0 = fmaf(RL(xa, k + 0), wr[k + 0], a0);
            a1 = fmaf(RL(xa, k + 1), wr[k + 1], a1);
            a2 = fmaf(RL(xa, k + 2), wr[k + 2], a2);
            a3 = fmaf(RL(xa, k + 3), wr[k + 3], a3);
        }
        if constexpr (K > 64) {
#pragma unroll
            for (int k = 0; k < 64; k += 4) {
                a0 = fmaf(RL(xb, k + 0), wr[64 + k + 0], a0);
                a1 = fmaf(RL(xb, k + 1), wr[64 + k + 1], a1);
                a2 = fmaf(RL(xb, k + 2), wr[64 + k + 2], a2);
                a3 = fmaf(RL(xb, k + 3), wr[64 + k + 3], a3);
            }
        }
        Y[r * 64 + lane] = dv * ((a0 + a1) + (a2 + a3));
        if (!more) break;
        r = rn;
        xa = xan;
        xb = xbn;
        dv = dvn;
    }
}

// ---------------- two-node fused gather-sum (16 outstanding gathers) ----------------
__device__ __forceinline__ void agg2(const float* __restrict__ Hp,
                                     const int* __restrict__ rowptr,
                                     const unsigned short* __restrict__ col,
                                     long vA, long vB, int j, bool hasB,
                                     float& sumA, float& sumB) {
    float a0 = Hp[vA * 64 + j], a1 = 0.f, a2 = 0.f, a3 = 0.f;
    float b0 = 0.f, b1 = 0.f, b2 = 0.f, b3 = 0.f;
    int pA = rowptr[vA], pA1 = rowptr[vA + 1];
    int pB = 0, pB1 = 0;
    if (hasB) { b0 = Hp[vB * 64 + j]; pB = rowptr[vB]; pB1 = rowptr[vB + 1]; }
    if ((pA & 1) && pA < pA1) { a1 += Hp[(long)col[pA] * 64 + j]; ++pA; }
    if ((pB & 1) && pB < pB1) { b1 += Hp[(long)col[pB] * 64 + j]; ++pB; }
    // fused main loop: both streams' loads issue from one basic block
    while (pA + 4 <= pA1 && pB + 4 <= pB1) {
        unsigned int cA01 = *(const unsigned int*)(col + pA);
        unsigned int cA23 = *(const unsigned int*)(col + pA + 2);
        unsigned int cB01 = *(const unsigned int*)(col + pB);
        unsigned int cB23 = *(const unsigned int*)(col + pB + 2);
        float hA0 = Hp[(long)(cA01 & 0xFFFFu) * 64 + j];
        float hA1 = Hp[(long)(cA01 >> 16) * 64 + j];
        float hA2 = Hp[(long)(cA23 & 0xFFFFu) * 64 + j];
        float hA3 = Hp[(long)(cA23 >> 16) * 64 + j];
        float hB0 = Hp[(long)(cB01 & 0xFFFFu) * 64 + j];
        float hB1 = Hp[(long)(cB01 >> 16) * 64 + j];
        float hB2 = Hp[(long)(cB23 & 0xFFFFu) * 64 + j];
        float hB3 = Hp[(long)(cB23 >> 16) * 64 + j];
        a0 += hA0; a1 += hA1; a2 += hA2; a3 += hA3;
        b0 += hB0; b1 += hB1; b2 += hB2; b3 += hB3;
        pA += 4; pB += 4;
    }
    for (; pA + 4 <= pA1; pA += 4) {
        unsigned int c01 = *(const unsigned int*)(col + pA);
        unsigned int c23 = *(const unsigned int*)(col + pA + 2);
        float h0 = Hp[(long)(c01 & 0xFFFFu) * 64 + j];
        float h1 = Hp[(long)(c01 >> 16) * 64 + j];
        float h2 = Hp[(long)(c23 & 0xFFFFu) * 64 + j];
        float h3 = Hp[(long)(c23 >> 16) * 64 + j];
        a0 += h0; a1 += h1; a2 += h2; a3 += h3;
    }
    for (; pA < pA1; ++pA) a1 += Hp[(long)col[pA] * 64 + j];
    for (; pB + 4 <= pB1; pB += 4) {
        unsigned int c01 = *(const unsigned int*)(col + pB);
        unsigned int c23 = *(const unsigned int*)(col + pB + 2);
        float h0 = Hp[(long)(c01 & 0xFFFFu) * 64 + j];
        float h1 = Hp[(long)(c01 >> 16) * 64 + j];
        float h2 = Hp[(long)(c23 & 0xFFFFu) * 64 + j];
        float h3 = Hp[(long)(c23 >> 16) * 64 + j];
        b0 += h0; b1 += h1; b2 += h2; b3 += h3;
    }
    for (; pB < pB1; ++pB) b1 += Hp[(long)col[pB] * 64 + j];
    sumA = (a0 + a1) + (a2 + a3);
    sumB = (b0 + b1) + (b2 + b3);
}

// ---------------- layer1-agg + layer2-GEMM fused, 2 nodes/wave ----------------
__global__ __launch_bounds__(256) void agg_gemm64(const float* __restrict__ Hp,
                                                  const int* __restrict__ rowptr,
                                                  const unsigned short* __restrict__ col,
                                                  const float* __restrict__ dinv,
                                                  const float* __restrict__ bias,
                                                  const float* __restrict__ W2,
                                                  float* __restrict__ out, int n) {
    const int j = threadIdx.x & 63;
    const long wid = (((long)blockIdx.x * blockDim.x) + threadIdx.x) >> 6;
    const long NW  = ((long)gridDim.x * blockDim.x) >> 6;
    float wr[64];
#pragma unroll
    for (int k = 0; k < 64; ++k) wr[k] = W2[k * 64 + j];
#pragma unroll
    for (int k = 0; k < 64; ++k) asm volatile("" : "+v"(wr[k]));  // pin in VGPRs
    const float bj = bias[j];
    for (long vA = wid; vA < n; vA += 2 * NW) {
        long vB = vA + NW;
        bool hasB = vB < n;
        float sA, sB;
        agg2(Hp, rowptr, col, vA, vB, j, hasB, sA, sB);
        float diA = dinv[vA];
        float diB = hasB ? dinv[vB] : 0.f;
        float gA = fmaxf(diA * sA + bj, 0.f);
        float gB = fmaxf(diB * sB + bj, 0.f);
        float a0 = 0.f, a1 = 0.f, a2 = 0.f, a3 = 0.f;
        float b0 = 0.f, b1 = 0.f, b2 = 0.f, b3 = 0.f;
#pragma unroll
        for (int k = 0; k < 64; k += 4) {
            float w0 = wr[k + 0], w1 = wr[k + 1], w2 = wr[k + 2], w3 = wr[k + 3];
            a0 = fmaf(RL(gA, k + 0), w0, a0);
            b0 = fmaf(RL(gB, k + 0), w0, b0);
            a1 = fmaf(RL(gA, k + 1), w1, a1);
            b1 = fmaf(RL(gB, k + 1), w1, b1);
            a2 = fmaf(RL(gA, k + 2), w2, a2);
            b2 = fmaf(RL(gB, k + 2), w2, b2);
            a3 = fmaf(RL(gA, k + 3), w3, a3);
            b3 = fmaf(RL(gB, k + 3), w3, b3);
        }
        out[vA * 64 + j] = diA * ((a0 + a1) + (a2 + a3));
        if (hasB) out[vB * 64 + j] = diB * ((b0 + b1) + (b2 + b3));
    }
}

// ---------------- layer2-agg + head-dot + pool, 2 nodes/wave ----------------
__global__ __launch_bounds__(256) void agg_pool(const float* __restrict__ Hp,
                                                const int* __restrict__ rowptr,
                                                const unsigned short* __restrict__ col,
                                                const float* __restrict__ dinv,
                                                const float* __restrict__ bias,
                                                const float* __restrict__ Wl,
                                                const int* __restrict__ batch,
                                                float* __restrict__ part,
                                                float* __restrict__ partc, int n) {
    __shared__ float lp[256];
    __shared__ float lc[256];
    lp[threadIdx.x] = 0.f;
    lc[threadIdx.x] = 0.f;
    __syncthreads();
    const int j  = threadIdx.x & 63;
    const int wv = threadIdx.x >> 6;
    const float bj  = bias[j];
    const float wlj = Wl[j];
    const long wid = (long)blockIdx.x * 4 + wv;
    const long NW  = (long)gridDim.x * 4;
    for (long vA = wid; vA < n; vA += 2 * NW) {
        long vB = vA + NW;
        bool hasB = vB < n;
        float sA, sB;
        agg2(Hp, rowptr, col, vA, vB, j, hasB, sA, sB);
        float diA = dinv[vA];
        float diB = hasB ? dinv[vB] : 0.f;
        float valA = fmaxf(diA * sA + bj, 0.f) * wlj;
        float valB = fmaxf(diB * sB + bj, 0.f) * wlj;
#pragma unroll
        for (int off = 32; off > 0; off >>= 1) {
            valA += __shfl_down(valA, off, 64);
            valB += __shfl_down(valB, off, 64);
        }
        if (j == 0) {
            atomicAdd(&lp[batch[vA]], valA);
            atomicAdd(&lc[batch[vA]], 1.0f);
            if (hasB) {
                atomicAdd(&lp[batch[vB]], valB);
                atomicAdd(&lc[batch[vB]], 1.0f);
            }
        }
    }
    __syncthreads();
    long o = (long)blockIdx.x * 256 + threadIdx.x;
    part[o]  = lp[threadIdx.x];
    partc[o] = lc[threadIdx.x];
}

__global__ __launch_bounds__(256) void pool_final(const float* __restrict__ part,
                                                  const float* __restrict__ partc,
                                                  const float* __restrict__ bl,
                                                  float* __restrict__ out, int nblk) {
    int g = blockIdx.x;
    int t = threadIdx.x;
    float s = 0.f, c = 0.f;
    for (int b = t; b < nblk; b += 256) {
        s += part[(long)b * 256 + g];
        c += partc[(long)b * 256 + g];
    }
    __shared__ float sp[256];
    __shared__ float sc[256];
    sp[t] = s;
    sc[t] = c;
    __syncthreads();
    for (int off = 128; off > 0; off >>= 1) {
        if (t < off) { sp[t] += sp[t + off]; sc[t] += sc[t + off]; }
        __syncthreads();
    }
    if (t == 0) out[g] = sp[0] / fmaxf(sc[0], 1.0f) + bl[0];
}

extern "C" void kernel_launch(void* const* d_in, const int* in_sizes, int n_in,
                              void* d_out, int out_size, void* d_ws, size_t ws_size,
                              hipStream_t stream) {
    const float* x  = (const float*)d_in[0];
    const float* W1 = (const float*)d_in[1];
    const float* b1 = (const float*)d_in[2];
    const float* W2 = (const float*)d_in[3];
    const float* b2 = (const float*)d_in[4];
    const float* Wl = (const float*)d_in[5];
    const float* bl = (const float*)d_in[6];
    const int* edge_index = (const int*)d_in[7];
    const int* batch      = (const int*)d_in[8];

    const int n = in_sizes[0] / 128;   // 50000 (< 65536 for ushort cols)
    const int E = in_sizes[7] / 2;     // 800000
    const int G = out_size;            // 256
    const int* src = edge_index;
    const int* dst = edge_index + E;

    char* ws = (char*)d_ws;
    size_t off = 0;
    auto alloc = [&](size_t bytes) { void* p = ws + off; off = (off + bytes + 255) & ~(size_t)255; return p; };
    int*            cntv   = (int*)           alloc((size_t)n * 4);
    float*          dinv   = (float*)         alloc((size_t)n * 4);
    int*            rowptr = (int*)           alloc((size_t)(n + 1) * 4);
    int*            cursor = (int*)           alloc((size_t)n * 4);
    int*            excl   = (int*)           alloc((size_t)n * 4);
    int*            sums   = (int*)           alloc((size_t)256 * 4);
    unsigned short* col    = (unsigned short*)alloc((size_t)E * 2);
    float*          bufA   = (float*)         alloc((size_t)n * 64 * 4);
    float*          bufB   = (float*)         alloc((size_t)n * 64 * 4);
    const int PBLK = 2048;
    float*          part   = (float*)         alloc((size_t)PBLK * 256 * 4);
    float*          partc  = (float*)         alloc((size_t)PBLK * 256 * 4);

    const int T = 256;
    const int nchunks = (n + 255) / 256;
    // ---- CSR build (shared by both layers) ----
    zero32<<<(n + T - 1) / T, T, 0, stream>>>(cntv, n);
    hist_dst<<<(E + T - 1) / T, T, 0, stream>>>(dst, cntv, E);
    dinv_from_cnt<<<(n + T - 1) / T, T, 0, stream>>>(cntv, dinv, n);
    scan1<<<nchunks, T, 0, stream>>>(cntv, excl, sums, n);
    scan2<<<1, T, 0, stream>>>(sums, nchunks);
    scan3<<<(n + 1 + T - 1) / T, T, 0, stream>>>(excl, sums, rowptr, cursor, n, E);
    fill_col16<<<1024, T, 0, stream>>>(src, dst, cursor, col, E, n);

    // ---- layer 1 GEMM (writes dinv-scaled h1') ----
    gemm_bcast_scaled<128><<<768, T, 0, stream>>>(x, W1, dinv, bufA, n);
    // ---- layer1-agg + layer2-GEMM fused (writes dinv-scaled h2') ----
    agg_gemm64<<<2048, T, 0, stream>>>(bufA, rowptr, col, dinv, b1, W2, bufB, n);
    // ---- layer2-agg + head + pooling partials ----
    agg_pool<<<PBLK, T, 0, stream>>>(bufB, rowptr, col, dinv, b2, Wl, batch, part, partc, n);
    pool_final<<<G, T, 0, stream>>>(part, partc, bl, (float*)d_out, PBLK);
}

// Round 12
// 203.421 us; speedup vs baseline: 1.1023x; 1.0373x over previous
//
#include <hip/hip_runtime.h>
#include <math.h>

// ---------------- small utils ----------------
__global__ void zero32(int* __restrict__ p, int n) {
    int i = blockIdx.x * blockDim.x + threadIdx.x;
    if (i < n) p[i] = 0;
}

// ---------------- degree ----------------
__global__ void hist_dst(const int* __restrict__ dst, int* __restrict__ cnt, int E) {
    int e = blockIdx.x * blockDim.x + threadIdx.x;
    if (e < E) atomicAdd(&cnt[dst[e]], 1);
}

// ---- hierarchical scan (+ fused dinv computation; scan1 loads cnt anyway) ----
__global__ __launch_bounds__(256) void scan1_dinv(const int* __restrict__ cnt,
                                                  int* __restrict__ excl,
                                                  int* __restrict__ sums,
                                                  float* __restrict__ dinv, int n) {
    int i = blockIdx.x * 256 + threadIdx.x;
    int v = (i < n) ? cnt[i] : 0;
    if (i < n) dinv[i] = rsqrtf((float)(v + 1));  // +1 self-loop
    int lane = threadIdx.x & 63;
    int w = threadIdx.x >> 6;
    int s = v;
#pragma unroll
    for (int off = 1; off < 64; off <<= 1) {
        int t = __shfl_up(s, off, 64);
        if (lane >= off) s += t;
    }
    __shared__ int wsum[4];
    if (lane == 63) wsum[w] = s;
    __syncthreads();
    int woff = 0;
#pragma unroll
    for (int k = 0; k < 3; ++k) if (k < w) woff += wsum[k];
    int incl = s + woff;
    if (i < n) excl[i] = incl - v;
    if (threadIdx.x == 255) sums[blockIdx.x] = incl;
}

__global__ __launch_bounds__(256) void scan2(int* __restrict__ sums, int nb) {
    int t = threadIdx.x;
    int v = (t < nb) ? sums[t] : 0;
    int lane = t & 63;
    int w = t >> 6;
    int s = v;
#pragma unroll
    for (int off = 1; off < 64; off <<= 1) {
        int u = __shfl_up(s, off, 64);
        if (lane >= off) s += u;
    }
    __shared__ int wsum[4];
    if (lane == 63) wsum[w] = s;
    __syncthreads();
    int woff = 0;
#pragma unroll
    for (int k = 0; k < 3; ++k) if (k < w) woff += wsum[k];
    int incl = s + woff;
    if (t < nb) sums[t] = incl - v;  // exclusive
}

__global__ __launch_bounds__(256) void scan3(const int* __restrict__ excl,
                                             const int* __restrict__ sums,
                                             int* __restrict__ rowptr,
                                             int* __restrict__ cursor, int n, int E) {
    int i = blockIdx.x * 256 + threadIdx.x;
    if (i < n) {
        int r = excl[i] + sums[i >> 8];
        rowptr[i] = r;
        cursor[i] = r;
    }
    if (i == n) rowptr[n] = E;
}

// XCD-partitioned fill; payload = src as ushort (n < 65536), weights factored
// into pre-scaled features.
__global__ void fill_col16(const int* __restrict__ src, const int* __restrict__ dst,
                           int* __restrict__ cursor, unsigned short* __restrict__ col,
                           int E, int n) {
    const int g    = blockIdx.x & 7;
    const int nblk = gridDim.x >> 3;
    const int bid  = blockIdx.x >> 3;
    const int lo = (int)(((long)g * n) >> 3);
    const int hi = (int)(((long)(g + 1) * n) >> 3);
    for (long e = (long)bid * blockDim.x + threadIdx.x; e < E;
         e += (long)nblk * blockDim.x) {
        int d = dst[e];
        if (d < lo || d >= hi) continue;
        int p = atomicAdd(&cursor[d], 1);
        col[p] = (unsigned short)src[e];
    }
}

#define RL(x, k) __int_as_float(__builtin_amdgcn_readlane(__float_as_int(x), (k)))

// ---------------- GEMM1: Y[n,64] = dinv[r] * (X[n,128] @ W[128,64]) ----------------
template <int K>
__global__ __launch_bounds__(256) void gemm_bcast_scaled(const float* __restrict__ X,
                                                         const float* __restrict__ W,
                                                         const float* __restrict__ dinv,
                                                         float* __restrict__ Y, int n) {
    const int lane = threadIdx.x & 63;
    const long wid = (((long)blockIdx.x * blockDim.x) + threadIdx.x) >> 6;
    const long nw  = ((long)gridDim.x * blockDim.x) >> 6;

    float wr[K];
#pragma unroll
    for (int k = 0; k < K; ++k) wr[k] = W[k * 64 + lane];
#pragma unroll
    for (int k = 0; k < K; ++k) asm volatile("" : "+v"(wr[k]));

    long r = wid;
    if (r >= n) return;
    float xa = X[r * K + lane];
    float xb = 0.f;
    if constexpr (K > 64) xb = X[r * K + 64 + lane];
    float dv = dinv[r];

    while (true) {
        long rn = r + nw;
        bool more = rn < n;
        long rc = more ? rn : r;
        float xan = X[rc * K + lane];
        float xbn = 0.f;
        if constexpr (K > 64) xbn = X[rc * K + 64 + lane];
        float dvn = dinv[rc];

        float a0 = 0.f, a1 = 0.f, a2 = 0.f, a3 = 0.f;
#pragma unroll
        for (int k = 0; k < 64; k += 4) {
            a0 = fmaf(RL(xa, k + 0), wr[k + 0], a0);
            a1 = fmaf(RL(xa, k + 1), wr[k + 1], a1);
            a2 = fmaf(RL(xa, k + 2), wr[k + 2], a2);
            a3 = fmaf(RL(xa, k + 3), wr[k + 3], a3);
        }
        if constexpr (K > 64) {
#pragma unroll
            for (int k = 0; k < 64; k += 4) {
                a0 = fmaf(RL(xb, k + 0), wr[64 + k + 0], a0);
                a1 = fmaf(RL(xb, k + 1), wr[64 + k + 1], a1);
                a2 = fmaf(RL(xb, k + 2), wr[64 + k + 2], a2);
                a3 = fmaf(RL(xb, k + 3), wr[64 + k + 3], a3);
            }
        }
        Y[r * 64 + lane] = dv * ((a0 + a1) + (a2 + a3));
        if (!more) break;
        r = rn;
        xa = xan;
        xb = xbn;
        dv = dvn;
    }
}

// ---------------- two-node gather-sum, software-pipelined col stream ----------------
// col words for iteration i+1 are issued BEFORE consuming iteration i's gathers,
// removing the col-load latency from the serial chain. col has >=16B slop past E.
__device__ __forceinline__ void agg2(const float* __restrict__ Hp,
                                     const int* __restrict__ rowptr,
                                     const unsigned short* __restrict__ col,
                                     long vA, long vB, int j, bool hasB,
                                     float& sumA, float& sumB) {
    float a0 = Hp[vA * 64 + j], a1 = 0.f, a2 = 0.f, a3 = 0.f;
    float b0 = 0.f, b1 = 0.f, b2 = 0.f, b3 = 0.f;
    int pA = rowptr[vA], pA1 = rowptr[vA + 1];
    int pB = 0, pB1 = 0;
    if (hasB) { b0 = Hp[vB * 64 + j]; pB = rowptr[vB]; pB1 = rowptr[vB + 1]; }
    if ((pA & 1) && pA < pA1) { a1 += Hp[(long)col[pA] * 64 + j]; ++pA; }
    if ((pB & 1) && pB < pB1) { b1 += Hp[(long)col[pB] * 64 + j]; ++pB; }
    // preload current col words (slop makes OOB-by-row reads safe)
    unsigned int cA01 = *(const unsigned int*)(col + pA);
    unsigned int cA23 = *(const unsigned int*)(col + pA + 2);
    unsigned int cB01 = *(const unsigned int*)(col + pB);
    unsigned int cB23 = *(const unsigned int*)(col + pB + 2);
    while (pA + 4 <= pA1 && pB + 4 <= pB1) {
        // issue next iteration's col loads first
        unsigned int nA01 = *(const unsigned int*)(col + pA + 4);
        unsigned int nA23 = *(const unsigned int*)(col + pA + 6);
        unsigned int nB01 = *(const unsigned int*)(col + pB + 4);
        unsigned int nB23 = *(const unsigned int*)(col + pB + 6);
        float hA0 = Hp[(long)(cA01 & 0xFFFFu) * 64 + j];
        float hA1 = Hp[(long)(cA01 >> 16) * 64 + j];
        float hA2 = Hp[(long)(cA23 & 0xFFFFu) * 64 + j];
        float hA3 = Hp[(long)(cA23 >> 16) * 64 + j];
        float hB0 = Hp[(long)(cB01 & 0xFFFFu) * 64 + j];
        float hB1 = Hp[(long)(cB01 >> 16) * 64 + j];
        float hB2 = Hp[(long)(cB23 & 0xFFFFu) * 64 + j];
        float hB3 = Hp[(long)(cB23 >> 16) * 64 + j];
        a0 += hA0; a1 += hA1; a2 += hA2; a3 += hA3;
        b0 += hB0; b1 += hB1; b2 += hB2; b3 += hB3;
        cA01 = nA01; cA23 = nA23; cB01 = nB01; cB23 = nB23;
        pA += 4; pB += 4;
    }
    // A tail (cA words valid for first iteration)
    for (; pA + 4 <= pA1; pA += 4) {
        float h0 = Hp[(long)(cA01 & 0xFFFFu) * 64 + j];
        float h1 = Hp[(long)(cA01 >> 16) * 64 + j];
        float h2 = Hp[(long)(cA23 & 0xFFFFu) * 64 + j];
        float h3 = Hp[(long)(cA23 >> 16) * 64 + j];
        a0 += h0; a1 += h1; a2 += h2; a3 += h3;
        cA01 = *(const unsigned int*)(col + pA + 4);
        cA23 = *(const unsigned int*)(col + pA + 6);
    }
    for (; pA < pA1; ++pA) a1 += Hp[(long)col[pA] * 64 + j];
    // B tail
    for (; pB + 4 <= pB1; pB += 4) {
        float h0 = Hp[(long)(cB01 & 0xFFFFu) * 64 + j];
        float h1 = Hp[(long)(cB01 >> 16) * 64 + j];
        float h2 = Hp[(long)(cB23 & 0xFFFFu) * 64 + j];
        float h3 = Hp[(long)(cB23 >> 16) * 64 + j];
        b0 += h0; b1 += h1; b2 += h2; b3 += h3;
        cB01 = *(const unsigned int*)(col + pB + 4);
        cB23 = *(const unsigned int*)(col + pB + 6);
    }
    for (; pB < pB1; ++pB) b1 += Hp[(long)col[pB] * 64 + j];
    sumA = (a0 + a1) + (a2 + a3);
    sumB = (b0 + b1) + (b2 + b3);
}

// ---------------- layer1-agg + layer2-GEMM fused, 2 nodes/wave ----------------
__global__ __launch_bounds__(256) void agg_gemm64(const float* __restrict__ Hp,
                                                  const int* __restrict__ rowptr,
                                                  const unsigned short* __restrict__ col,
                                                  const float* __restrict__ dinv,
                                                  const float* __restrict__ bias,
                                                  const float* __restrict__ W2,
                                                  float* __restrict__ out, int n) {
    const int j = threadIdx.x & 63;
    const long wid = (((long)blockIdx.x * blockDim.x) + threadIdx.x) >> 6;
    const long NW  = ((long)gridDim.x * blockDim.x) >> 6;
    float wr[64];
#pragma unroll
    for (int k = 0; k < 64; ++k) wr[k] = W2[k * 64 + j];
#pragma unroll
    for (int k = 0; k < 64; ++k) asm volatile("" : "+v"(wr[k]));
    const float bj = bias[j];
    for (long vA = wid; vA < n; vA += 2 * NW) {
        long vB = vA + NW;
        bool hasB = vB < n;
        float sA, sB;
        agg2(Hp, rowptr, col, vA, vB, j, hasB, sA, sB);
        float diA = dinv[vA];
        float diB = hasB ? dinv[vB] : 0.f;
        float gA = fmaxf(diA * sA + bj, 0.f);
        float gB = fmaxf(diB * sB + bj, 0.f);
        float a0 = 0.f, a1 = 0.f, a2 = 0.f, a3 = 0.f;
        float b0 = 0.f, b1 = 0.f, b2 = 0.f, b3 = 0.f;
#pragma unroll
        for (int k = 0; k < 64; k += 4) {
            float w0 = wr[k + 0], w1 = wr[k + 1], w2 = wr[k + 2], w3 = wr[k + 3];
            a0 = fmaf(RL(gA, k + 0), w0, a0);
            b0 = fmaf(RL(gB, k + 0), w0, b0);
            a1 = fmaf(RL(gA, k + 1), w1, a1);
            b1 = fmaf(RL(gB, k + 1), w1, b1);
            a2 = fmaf(RL(gA, k + 2), w2, a2);
            b2 = fmaf(RL(gB, k + 2), w2, b2);
            a3 = fmaf(RL(gA, k + 3), w3, a3);
            b3 = fmaf(RL(gB, k + 3), w3, b3);
        }
        out[vA * 64 + j] = diA * ((a0 + a1) + (a2 + a3));
        if (hasB) out[vB * 64 + j] = diB * ((b0 + b1) + (b2 + b3));
    }
}

// ---------------- layer2-agg + head-dot + pool, 2 nodes/wave ----------------
__global__ __launch_bounds__(256) void agg_pool(const float* __restrict__ Hp,
                                                const int* __restrict__ rowptr,
                                                const unsigned short* __restrict__ col,
                                                const float* __restrict__ dinv,
                                                const float* __restrict__ bias,
                                                const float* __restrict__ Wl,
                                                const int* __restrict__ batch,
                                                float* __restrict__ part,
                                                float* __restrict__ partc, int n) {
    __shared__ float lp[256];
    __shared__ float lc[256];
    lp[threadIdx.x] = 0.f;
    lc[threadIdx.x] = 0.f;
    __syncthreads();
    const int j  = threadIdx.x & 63;
    const int wv = threadIdx.x >> 6;
    const float bj  = bias[j];
    const float wlj = Wl[j];
    const long wid = (long)blockIdx.x * 4 + wv;
    const long NW  = (long)gridDim.x * 4;
    for (long vA = wid; vA < n; vA += 2 * NW) {
        long vB = vA + NW;
        bool hasB = vB < n;
        float sA, sB;
        agg2(Hp, rowptr, col, vA, vB, j, hasB, sA, sB);
        float diA = dinv[vA];
        float diB = hasB ? dinv[vB] : 0.f;
        float valA = fmaxf(diA * sA + bj, 0.f) * wlj;
        float valB = fmaxf(diB * sB + bj, 0.f) * wlj;
#pragma unroll
        for (int off = 32; off > 0; off >>= 1) {
            valA += __shfl_down(valA, off, 64);
            valB += __shfl_down(valB, off, 64);
        }
        if (j == 0) {
            atomicAdd(&lp[batch[vA]], valA);
            atomicAdd(&lc[batch[vA]], 1.0f);
            if (hasB) {
                atomicAdd(&lp[batch[vB]], valB);
                atomicAdd(&lc[batch[vB]], 1.0f);
            }
        }
    }
    __syncthreads();
    long o = (long)blockIdx.x * 256 + threadIdx.x;
    part[o]  = lp[threadIdx.x];
    partc[o] = lc[threadIdx.x];
}

__global__ __launch_bounds__(256) void pool_final(const float* __restrict__ part,
                                                  const float* __restrict__ partc,
                                                  const float* __restrict__ bl,
                                                  float* __restrict__ out, int nblk) {
    int g = blockIdx.x;
    int t = threadIdx.x;
    float s = 0.f, c = 0.f;
    for (int b = t; b < nblk; b += 256) {
        s += part[(long)b * 256 + g];
        c += partc[(long)b * 256 + g];
    }
    __shared__ float sp[256];
    __shared__ float sc[256];
    sp[t] = s;
    sc[t] = c;
    __syncthreads();
    for (int off = 128; off > 0; off >>= 1) {
        if (t < off) { sp[t] += sp[t + off]; sc[t] += sc[t + off]; }
        __syncthreads();
    }
    if (t == 0) out[g] = sp[0] / fmaxf(sc[0], 1.0f) + bl[0];
}

extern "C" void kernel_launch(void* const* d_in, const int* in_sizes, int n_in,
                              void* d_out, int out_size, void* d_ws, size_t ws_size,
                              hipStream_t stream) {
    const float* x  = (const float*)d_in[0];
    const float* W1 = (const float*)d_in[1];
    const float* b1 = (const float*)d_in[2];
    const float* W2 = (const float*)d_in[3];
    const float* b2 = (const float*)d_in[4];
    const float* Wl = (const float*)d_in[5];
    const float* bl = (const float*)d_in[6];
    const int* edge_index = (const int*)d_in[7];
    const int* batch      = (const int*)d_in[8];

    const int n = in_sizes[0] / 128;   // 50000 (< 65536 for ushort cols)
    const int E = in_sizes[7] / 2;     // 800000
    const int G = out_size;            // 256
    const int* src = edge_index;
    const int* dst = edge_index + E;

    char* ws = (char*)d_ws;
    size_t off = 0;
    auto alloc = [&](size_t bytes) { void* p = ws + off; off = (off + bytes + 255) & ~(size_t)255; return p; };
    int*            cntv   = (int*)           alloc((size_t)n * 4);
    float*          dinv   = (float*)         alloc((size_t)n * 4);
    int*            rowptr = (int*)           alloc((size_t)(n + 1) * 4);
    int*            cursor = (int*)           alloc((size_t)n * 4);
    int*            excl   = (int*)           alloc((size_t)n * 4);
    int*            sums   = (int*)           alloc((size_t)256 * 4);
    unsigned short* col    = (unsigned short*)alloc((size_t)E * 2 + 64);  // +slop for prefetch
    float*          bufA   = (float*)         alloc((size_t)n * 64 * 4);
    float*          bufB   = (float*)         alloc((size_t)n * 64 * 4);
    const int PBLK = 2048;
    float*          part   = (float*)         alloc((size_t)PBLK * 256 * 4);
    float*          partc  = (float*)         alloc((size_t)PBLK * 256 * 4);

    const int T = 256;
    const int nchunks = (n + 255) / 256;
    // ---- CSR build (shared by both layers) ----
    zero32<<<(n + T - 1) / T, T, 0, stream>>>(cntv, n);
    hist_dst<<<(E + T - 1) / T, T, 0, stream>>>(dst, cntv, E);
    scan1_dinv<<<nchunks, T, 0, stream>>>(cntv, excl, sums, dinv, n);
    scan2<<<1, T, 0, stream>>>(sums, nchunks);
    scan3<<<(n + 1 + T - 1) / T, T, 0, stream>>>(excl, sums, rowptr, cursor, n, E);
    fill_col16<<<1024, T, 0, stream>>>(src, dst, cursor, col, E, n);

    // ---- layer 1 GEMM (writes dinv-scaled h1') ----
    gemm_bcast_scaled<128><<<768, T, 0, stream>>>(x, W1, dinv, bufA, n);
    // ---- layer1-agg + layer2-GEMM fused (writes dinv-scaled h2') ----
    agg_gemm64<<<2048, T, 0, stream>>>(bufA, rowptr, col, dinv, b1, W2, bufB, n);
    // ---- layer2-agg + head + pooling partials ----
    agg_pool<<<PBLK, T, 0, stream>>>(bufB, rowptr, col, dinv, b2, Wl, batch, part, partc, n);
    pool_final<<<G, T, 0, stream>>>(part, partc, bl, (float*)d_out, PBLK);
}

// Round 13
// 186.407 us; speedup vs baseline: 1.2029x; 1.0913x over previous
//
#include <hip/hip_runtime.h>
#include <math.h>

// ---------------- small utils ----------------
__global__ void zero32(int* __restrict__ p, int n) {
    int i = blockIdx.x * blockDim.x + threadIdx.x;
    if (i < n) p[i] = 0;
}

// ---------------- degree + per-edge rank (counting-sort split) ----------------
// rank[e] = arrival index of edge e at its dst -> placement needs no atomics.
__global__ void hist_rank(const int* __restrict__ dst, int* __restrict__ cnt,
                          unsigned short* __restrict__ rank, int E) {
    int e = blockIdx.x * blockDim.x + threadIdx.x;
    if (e < E) rank[e] = (unsigned short)atomicAdd(&cnt[dst[e]], 1);
}

// ---- hierarchical scan (+ fused dinv computation) ----
__global__ __launch_bounds__(256) void scan1_dinv(const int* __restrict__ cnt,
                                                  int* __restrict__ excl,
                                                  int* __restrict__ sums,
                                                  float* __restrict__ dinv, int n) {
    int i = blockIdx.x * 256 + threadIdx.x;
    int v = (i < n) ? cnt[i] : 0;
    if (i < n) dinv[i] = rsqrtf((float)(v + 1));  // +1 self-loop
    int lane = threadIdx.x & 63;
    int w = threadIdx.x >> 6;
    int s = v;
#pragma unroll
    for (int off = 1; off < 64; off <<= 1) {
        int t = __shfl_up(s, off, 64);
        if (lane >= off) s += t;
    }
    __shared__ int wsum[4];
    if (lane == 63) wsum[w] = s;
    __syncthreads();
    int woff = 0;
#pragma unroll
    for (int k = 0; k < 3; ++k) if (k < w) woff += wsum[k];
    int incl = s + woff;
    if (i < n) excl[i] = incl - v;
    if (threadIdx.x == 255) sums[blockIdx.x] = incl;
}

__global__ __launch_bounds__(256) void scan2(int* __restrict__ sums, int nb) {
    int t = threadIdx.x;
    int v = (t < nb) ? sums[t] : 0;
    int lane = t & 63;
    int w = t >> 6;
    int s = v;
#pragma unroll
    for (int off = 1; off < 64; off <<= 1) {
        int u = __shfl_up(s, off, 64);
        if (lane >= off) s += u;
    }
    __shared__ int wsum[4];
    if (lane == 63) wsum[w] = s;
    __syncthreads();
    int woff = 0;
#pragma unroll
    for (int k = 0; k < 3; ++k) if (k < w) woff += wsum[k];
    int incl = s + woff;
    if (t < nb) sums[t] = incl - v;  // exclusive
}

__global__ __launch_bounds__(256) void scan3(const int* __restrict__ excl,
                                             const int* __restrict__ sums,
                                             int* __restrict__ rowptr, int n, int E) {
    int i = blockIdx.x * 256 + threadIdx.x;
    if (i < n) rowptr[i] = excl[i] + sums[i >> 8];
    if (i == n) rowptr[n] = E;
}

// atomic-free placement, XCD-partitioned for col write locality
__global__ void fill_place(const int* __restrict__ src, const int* __restrict__ dst,
                           const unsigned short* __restrict__ rank,
                           const int* __restrict__ rowptr,
                           unsigned short* __restrict__ col, int E, int n) {
    const int g    = blockIdx.x & 7;
    const int nblk = gridDim.x >> 3;
    const int bid  = blockIdx.x >> 3;
    const int lo = (int)(((long)g * n) >> 3);
    const int hi = (int)(((long)(g + 1) * n) >> 3);
    for (long e = (long)bid * blockDim.x + threadIdx.x; e < E;
         e += (long)nblk * blockDim.x) {
        int d = dst[e];
        if (d < lo || d >= hi) continue;
        col[rowptr[d] + rank[e]] = (unsigned short)src[e];
    }
}

#define RL(x, k) __int_as_float(__builtin_amdgcn_readlane(__float_as_int(x), (k)))

// ---------------- GEMM1: Y[n,64] = dinv[r] * (X[n,128] @ W[128,64]) ----------------
// depth-2 row prefetch: row r+2's loads issue while r computes -> ~2 compute
// blocks (512cy) cover the ~900cy HBM latency.
template <int K>
__global__ __launch_bounds__(256) void gemm_bcast_scaled(const float* __restrict__ X,
                                                         const float* __restrict__ W,
                                                         const float* __restrict__ dinv,
                                                         float* __restrict__ Y, int n) {
    const int lane = threadIdx.x & 63;
    const long wid = (((long)blockIdx.x * blockDim.x) + threadIdx.x) >> 6;
    const long nw  = ((long)gridDim.x * blockDim.x) >> 6;

    float wr[K];
#pragma unroll
    for (int k = 0; k < K; ++k) wr[k] = W[k * 64 + lane];
#pragma unroll
    for (int k = 0; k < K; ++k) asm volatile("" : "+v"(wr[k]));

    long r0 = wid;
    if (r0 >= n) return;
    float xa0 = X[r0 * K + lane];
    float xb0 = 0.f;
    if constexpr (K > 64) xb0 = X[r0 * K + 64 + lane];
    float dv0 = dinv[r0];

    long r1 = r0 + nw;
    bool h1 = r1 < n;
    long rc1 = h1 ? r1 : r0;
    float xa1 = X[rc1 * K + lane];
    float xb1 = 0.f;
    if constexpr (K > 64) xb1 = X[rc1 * K + 64 + lane];
    float dv1 = dinv[rc1];

    while (true) {
        long r2 = r1 + nw;
        bool h2 = h1 && (r2 < n);
        long rc2 = h2 ? r2 : r0;
        float xa2 = X[rc2 * K + lane];
        float xb2 = 0.f;
        if constexpr (K > 64) xb2 = X[rc2 * K + 64 + lane];
        float dv2 = dinv[rc2];

        float a0 = 0.f, a1 = 0.f, a2 = 0.f, a3 = 0.f;
#pragma unroll
        for (int k = 0; k < 64; k += 4) {
            a0 = fmaf(RL(xa0, k + 0), wr[k + 0], a0);
            a1 = fmaf(RL(xa0, k + 1), wr[k + 1], a1);
            a2 = fmaf(RL(xa0, k + 2), wr[k + 2], a2);
            a3 = fmaf(RL(xa0, k + 3), wr[k + 3], a3);
        }
        if constexpr (K > 64) {
#pragma unroll
            for (int k = 0; k < 64; k += 4) {
                a0 = fmaf(RL(xb0, k + 0), wr[64 + k + 0], a0);
                a1 = fmaf(RL(xb0, k + 1), wr[64 + k + 1], a1);
                a2 = fmaf(RL(xb0, k + 2), wr[64 + k + 2], a2);
                a3 = fmaf(RL(xb0, k + 3), wr[64 + k + 3], a3);
            }
        }
        Y[r0 * 64 + lane] = dv0 * ((a0 + a1) + (a2 + a3));
        if (!h1) break;
        r0 = r1; xa0 = xa1; xb0 = xb1; dv0 = dv1;
        r1 = r2; h1 = h2; xa1 = xa2; xb1 = xb2; dv1 = dv2;
    }
}

// ---------------- two-node gather-sum, software-pipelined col stream ----------------
__device__ __forceinline__ void agg2(const float* __restrict__ Hp,
                                     const int* __restrict__ rowptr,
                                     const unsigned short* __restrict__ col,
                                     long vA, long vB, int j, bool hasB,
                                     float& sumA, float& sumB) {
    float a0 = Hp[vA * 64 + j], a1 = 0.f, a2 = 0.f, a3 = 0.f;
    float b0 = 0.f, b1 = 0.f, b2 = 0.f, b3 = 0.f;
    int pA = rowptr[vA], pA1 = rowptr[vA + 1];
    int pB = 0, pB1 = 0;
    if (hasB) { b0 = Hp[vB * 64 + j]; pB = rowptr[vB]; pB1 = rowptr[vB + 1]; }
    if ((pA & 1) && pA < pA1) { a1 += Hp[(long)col[pA] * 64 + j]; ++pA; }
    if ((pB & 1) && pB < pB1) { b1 += Hp[(long)col[pB] * 64 + j]; ++pB; }
    unsigned int cA01 = *(const unsigned int*)(col + pA);
    unsigned int cA23 = *(const unsigned int*)(col + pA + 2);
    unsigned int cB01 = *(const unsigned int*)(col + pB);
    unsigned int cB23 = *(const unsigned int*)(col + pB + 2);
    while (pA + 4 <= pA1 && pB + 4 <= pB1) {
        unsigned int nA01 = *(const unsigned int*)(col + pA + 4);
        unsigned int nA23 = *(const unsigned int*)(col + pA + 6);
        unsigned int nB01 = *(const unsigned int*)(col + pB + 4);
        unsigned int nB23 = *(const unsigned int*)(col + pB + 6);
        float hA0 = Hp[(long)(cA01 & 0xFFFFu) * 64 + j];
        float hA1 = Hp[(long)(cA01 >> 16) * 64 + j];
        float hA2 = Hp[(long)(cA23 & 0xFFFFu) * 64 + j];
        float hA3 = Hp[(long)(cA23 >> 16) * 64 + j];
        float hB0 = Hp[(long)(cB01 & 0xFFFFu) * 64 + j];
        float hB1 = Hp[(long)(cB01 >> 16) * 64 + j];
        float hB2 = Hp[(long)(cB23 & 0xFFFFu) * 64 + j];
        float hB3 = Hp[(long)(cB23 >> 16) * 64 + j];
        a0 += hA0; a1 += hA1; a2 += hA2; a3 += hA3;
        b0 += hB0; b1 += hB1; b2 += hB2; b3 += hB3;
        cA01 = nA01; cA23 = nA23; cB01 = nB01; cB23 = nB23;
        pA += 4; pB += 4;
    }
    for (; pA + 4 <= pA1; pA += 4) {
        float h0 = Hp[(long)(cA01 & 0xFFFFu) * 64 + j];
        float h1 = Hp[(long)(cA01 >> 16) * 64 + j];
        float h2 = Hp[(long)(cA23 & 0xFFFFu) * 64 + j];
        float h3 = Hp[(long)(cA23 >> 16) * 64 + j];
        a0 += h0; a1 += h1; a2 += h2; a3 += h3;
        cA01 = *(const unsigned int*)(col + pA + 4);
        cA23 = *(const unsigned int*)(col + pA + 6);
    }
    for (; pA < pA1; ++pA) a1 += Hp[(long)col[pA] * 64 + j];
    for (; pB + 4 <= pB1; pB += 4) {
        float h0 = Hp[(long)(cB01 & 0xFFFFu) * 64 + j];
        float h1 = Hp[(long)(cB01 >> 16) * 64 + j];
        float h2 = Hp[(long)(cB23 & 0xFFFFu) * 64 + j];
        float h3 = Hp[(long)(cB23 >> 16) * 64 + j];
        b0 += h0; b1 += h1; b2 += h2; b3 += h3;
        cB01 = *(const unsigned int*)(col + pB + 4);
        cB23 = *(const unsigned int*)(col + pB + 6);
    }
    for (; pB < pB1; ++pB) b1 += Hp[(long)col[pB] * 64 + j];
    sumA = (a0 + a1) + (a2 + a3);
    sumB = (b0 + b1) + (b2 + b3);
}

// ---------------- layer1-agg + layer2-GEMM fused, 2 nodes/wave ----------------
__global__ __launch_bounds__(256) void agg_gemm64(const float* __restrict__ Hp,
                                                  const int* __restrict__ rowptr,
                                                  const unsigned short* __restrict__ col,
                                                  const float* __restrict__ dinv,
                                                  const float* __restrict__ bias,
                                                  const float* __restrict__ W2,
                                                  float* __restrict__ out, int n) {
    const int j = threadIdx.x & 63;
    const long wid = (((long)blockIdx.x * blockDim.x) + threadIdx.x) >> 6;
    const long NW  = ((long)gridDim.x * blockDim.x) >> 6;
    float wr[64];
#pragma unroll
    for (int k = 0; k < 64; ++k) wr[k] = W2[k * 64 + j];
#pragma unroll
    for (int k = 0; k < 64; ++k) asm volatile("" : "+v"(wr[k]));
    const float bj = bias[j];
    for (long vA = wid; vA < n; vA += 2 * NW) {
        long vB = vA + NW;
        bool hasB = vB < n;
        float sA, sB;
        agg2(Hp, rowptr, col, vA, vB, j, hasB, sA, sB);
        float diA = dinv[vA];
        float diB = hasB ? dinv[vB] : 0.f;
        float gA = fmaxf(diA * sA + bj, 0.f);
        float gB = fmaxf(diB * sB + bj, 0.f);
        float a0 = 0.f, a1 = 0.f, a2 = 0.f, a3 = 0.f;
        float b0 = 0.f, b1 = 0.f, b2 = 0.f, b3 = 0.f;
#pragma unroll
        for (int k = 0; k < 64; k += 4) {
            float w0 = wr[k + 0], w1 = wr[k + 1], w2 = wr[k + 2], w3 = wr[k + 3];
            a0 = fmaf(RL(gA, k + 0), w0, a0);
            b0 = fmaf(RL(gB, k + 0), w0, b0);
            a1 = fmaf(RL(gA, k + 1), w1, a1);
            b1 = fmaf(RL(gB, k + 1), w1, b1);
            a2 = fmaf(RL(gA, k + 2), w2, a2);
            b2 = fmaf(RL(gB, k + 2), w2, b2);
            a3 = fmaf(RL(gA, k + 3), w3, a3);
            b3 = fmaf(RL(gB, k + 3), w3, b3);
        }
        out[vA * 64 + j] = diA * ((a0 + a1) + (a2 + a3));
        if (hasB) out[vB * 64 + j] = diB * ((b0 + b1) + (b2 + b3));
    }
}

// ---------------- layer2-agg + head-dot + pool, 2 nodes/wave ----------------
__global__ __launch_bounds__(256) void agg_pool(const float* __restrict__ Hp,
                                                const int* __restrict__ rowptr,
                                                const unsigned short* __restrict__ col,
                                                const float* __restrict__ dinv,
                                                const float* __restrict__ bias,
                                                const float* __restrict__ Wl,
                                                const int* __restrict__ batch,
                                                float* __restrict__ part,
                                                float* __restrict__ partc, int n) {
    __shared__ float lp[256];
    __shared__ float lc[256];
    lp[threadIdx.x] = 0.f;
    lc[threadIdx.x] = 0.f;
    __syncthreads();
    const int j  = threadIdx.x & 63;
    const int wv = threadIdx.x >> 6;
    const float bj  = bias[j];
    const float wlj = Wl[j];
    const long wid = (long)blockIdx.x * 4 + wv;
    const long NW  = (long)gridDim.x * 4;
    for (long vA = wid; vA < n; vA += 2 * NW) {
        long vB = vA + NW;
        bool hasB = vB < n;
        float sA, sB;
        agg2(Hp, rowptr, col, vA, vB, j, hasB, sA, sB);
        float diA = dinv[vA];
        float diB = hasB ? dinv[vB] : 0.f;
        float valA = fmaxf(diA * sA + bj, 0.f) * wlj;
        float valB = fmaxf(diB * sB + bj, 0.f) * wlj;
#pragma unroll
        for (int off = 32; off > 0; off >>= 1) {
            valA += __shfl_down(valA, off, 64);
            valB += __shfl_down(valB, off, 64);
        }
        if (j == 0) {
            atomicAdd(&lp[batch[vA]], valA);
            atomicAdd(&lc[batch[vA]], 1.0f);
            if (hasB) {
                atomicAdd(&lp[batch[vB]], valB);
                atomicAdd(&lc[batch[vB]], 1.0f);
            }
        }
    }
    __syncthreads();
    long o = (long)blockIdx.x * 256 + threadIdx.x;
    part[o]  = lp[threadIdx.x];
    partc[o] = lc[threadIdx.x];
}

__global__ __launch_bounds__(256) void pool_final(const float* __restrict__ part,
                                                  const float* __restrict__ partc,
                                                  const float* __restrict__ bl,
                                                  float* __restrict__ out, int nblk) {
    int g = blockIdx.x;
    int t = threadIdx.x;
    float s = 0.f, c = 0.f;
    for (int b = t; b < nblk; b += 256) {
        s += part[(long)b * 256 + g];
        c += partc[(long)b * 256 + g];
    }
    __shared__ float sp[256];
    __shared__ float sc[256];
    sp[t] = s;
    sc[t] = c;
    __syncthreads();
    for (int off = 128; off > 0; off >>= 1) {
        if (t < off) { sp[t] += sp[t + off]; sc[t] += sc[t + off]; }
        __syncthreads();
    }
    if (t == 0) out[g] = sp[0] / fmaxf(sc[0], 1.0f) + bl[0];
}

extern "C" void kernel_launch(void* const* d_in, const int* in_sizes, int n_in,
                              void* d_out, int out_size, void* d_ws, size_t ws_size,
                              hipStream_t stream) {
    const float* x  = (const float*)d_in[0];
    const float* W1 = (const float*)d_in[1];
    const float* b1 = (const float*)d_in[2];
    const float* W2 = (const float*)d_in[3];
    const float* b2 = (const float*)d_in[4];
    const float* Wl = (const float*)d_in[5];
    const float* bl = (const float*)d_in[6];
    const int* edge_index = (const int*)d_in[7];
    const int* batch      = (const int*)d_in[8];

    const int n = in_sizes[0] / 128;   // 50000 (< 65536 for ushort cols)
    const int E = in_sizes[7] / 2;     // 800000
    const int G = out_size;            // 256
    const int* src = edge_index;
    const int* dst = edge_index + E;

    char* ws = (char*)d_ws;
    size_t off = 0;
    auto alloc = [&](size_t bytes) { void* p = ws + off; off = (off + bytes + 255) & ~(size_t)255; return p; };
    int*            cntv   = (int*)           alloc((size_t)n * 4);
    float*          dinv   = (float*)         alloc((size_t)n * 4);
    int*            rowptr = (int*)           alloc((size_t)(n + 1) * 4);
    int*            excl   = (int*)           alloc((size_t)n * 4);
    int*            sums   = (int*)           alloc((size_t)256 * 4);
    unsigned short* rank   = (unsigned short*)alloc((size_t)E * 2);
    unsigned short* col    = (unsigned short*)alloc((size_t)E * 2 + 64);  // +slop for prefetch
    float*          bufA   = (float*)         alloc((size_t)n * 64 * 4);
    float*          bufB   = (float*)         alloc((size_t)n * 64 * 4);
    const int PBLK = 2048;
    float*          part   = (float*)         alloc((size_t)PBLK * 256 * 4);
    float*          partc  = (float*)         alloc((size_t)PBLK * 256 * 4);

    const int T = 256;
    const int nchunks = (n + 255) / 256;
    // ---- CSR build (shared by both layers) ----
    zero32<<<(n + T - 1) / T, T, 0, stream>>>(cntv, n);
    hist_rank<<<(E + T - 1) / T, T, 0, stream>>>(dst, cntv, rank, E);
    scan1_dinv<<<nchunks, T, 0, stream>>>(cntv, excl, sums, dinv, n);
    scan2<<<1, T, 0, stream>>>(sums, nchunks);
    scan3<<<(n + 1 + T - 1) / T, T, 0, stream>>>(excl, sums, rowptr, n, E);
    fill_place<<<1024, T, 0, stream>>>(src, dst, rank, rowptr, col, E, n);

    // ---- layer 1 GEMM (writes dinv-scaled h1') ----
    gemm_bcast_scaled<128><<<768, T, 0, stream>>>(x, W1, dinv, bufA, n);
    // ---- layer1-agg + layer2-GEMM fused (writes dinv-scaled h2') ----
    agg_gemm64<<<2048, T, 0, stream>>>(bufA, rowptr, col, dinv, b1, W2, bufB, n);
    // ---- layer2-agg + head + pooling partials ----
    agg_pool<<<PBLK, T, 0, stream>>>(bufB, rowptr, col, dinv, b2, Wl, batch, part, partc, n);
    pool_final<<<G, T, 0, stream>>>(part, partc, bl, (float*)d_out, PBLK);
}